// Round 1
// baseline (113.477 us; speedup 1.0000x reference)
//
#include <hip/hip_runtime.h>

// ClinicalSafetyLoss: fused CE + penalty-matrix + critical-miss reduction.
// Memory-bound streaming: 48 MiB logits + 16 MiB targets -> 1 scalar.

__device__ __forceinline__ float wave_reduce_f(float v) {
#pragma unroll
    for (int off = 32; off > 0; off >>= 1) v += __shfl_down(v, off, 64);
    return v;
}
__device__ __forceinline__ int wave_reduce_i(int v) {
#pragma unroll
    for (int off = 32; off > 0; off >>= 1) v += __shfl_down(v, off, 64);
    return v;
}

__global__ void __launch_bounds__(256) loss_main_kernel(
    const float* __restrict__ logits, const int* __restrict__ tgt,
    int nquads, double* __restrict__ ws_d, unsigned int* __restrict__ ws_u) {
    float ce = 0.0f, pen = 0.0f;
    int crit = 0, miss = 0;

    const float4* lv = reinterpret_cast<const float4*>(logits);
    const int4*   tv = reinterpret_cast<const int4*>(tgt);

    const int stride = gridDim.x * blockDim.x;
    for (int q = blockIdx.x * blockDim.x + threadIdx.x; q < nquads; q += stride) {
        // 4 samples = 12 floats = 3 x float4 (48B per thread, 16B-aligned), 1 x int4
        float4 a = lv[3 * q + 0];
        float4 b = lv[3 * q + 1];
        float4 c = lv[3 * q + 2];
        int4   t4 = tv[q];

        float x[12] = {a.x, a.y, a.z, a.w, b.x, b.y, b.z, b.w, c.x, c.y, c.z, c.w};
        int   t[4]  = {t4.x, t4.y, t4.z, t4.w};

#pragma unroll
        for (int s = 0; s < 4; ++s) {   // fully unrolled -> all indices static (regs, no scratch)
            const float x0 = x[3 * s + 0], x1 = x[3 * s + 1], x2 = x[3 * s + 2];
            const int tg = t[s];

            // argmax, first-occurrence on ties (strict >) == jnp.argmax
            int pred = 0;
            float best = x0;
            if (x1 > best) { best = x1; pred = 1; }
            if (x2 > best) { best = x2; pred = 2; }

            // log-sum-exp (max-subtracted)
            const float e0 = __expf(x0 - best);
            const float e1 = __expf(x1 - best);
            const float e2 = __expf(x2 - best);
            const float lse = best + __logf(e0 + e1 + e2);
            const float xt = (tg == 0) ? x0 : ((tg == 1) ? x1 : x2);
            ce += (lse - xt);   // -logp[target]

            // PENALTY_MATRIX[tg][pred] via select chain (no memory, no scratch array)
            float pv;
            if (tg == 0)      pv = (float)pred;                                   // 0,1,2
            else if (tg == 1) pv = (pred == 0) ? 5.0f : ((pred == 1) ? 0.0f : 1.0f);
            else              pv = (pred == 0) ? 20.0f : ((pred == 1) ? 10.0f : 0.0f);
            pen += pv;

            const int is_crit = (tg == 2);
            crit += is_crit;
            miss += is_crit & (pred != 2);
        }
    }

    // wave -> block -> global reduction
    ce   = wave_reduce_f(ce);
    pen  = wave_reduce_f(pen);
    crit = wave_reduce_i(crit);
    miss = wave_reduce_i(miss);

    __shared__ float s_ce[4], s_pen[4];
    __shared__ int   s_cr[4], s_mi[4];
    const int lane = threadIdx.x & 63;
    const int wid  = threadIdx.x >> 6;
    if (lane == 0) { s_ce[wid] = ce; s_pen[wid] = pen; s_cr[wid] = crit; s_mi[wid] = miss; }
    __syncthreads();
    if (threadIdx.x == 0) {
        float tc = 0.0f, tp = 0.0f;
        int cr = 0, mi = 0;
#pragma unroll
        for (int i = 0; i < 4; ++i) { tc += s_ce[i]; tp += s_pen[i]; cr += s_cr[i]; mi += s_mi[i]; }
        atomicAdd(&ws_d[0], (double)tc);
        atomicAdd(&ws_d[1], (double)tp);
        atomicAdd(&ws_u[0], (unsigned int)cr);
        atomicAdd(&ws_u[1], (unsigned int)mi);
    }
}

__global__ void loss_final_kernel(const double* __restrict__ ws_d,
                                  const unsigned int* __restrict__ ws_u,
                                  const float* __restrict__ logits,
                                  const int* __restrict__ tgt,
                                  int start, int total, float* __restrict__ out) {
    double ce = ws_d[0], pen = ws_d[1];
    unsigned int cr = ws_u[0], mi = ws_u[1];

    // scalar tail (B % 4 != 0); B = 4194304 -> empty loop
    for (int i = start; i < total; ++i) {
        const float x0 = logits[3 * i + 0], x1 = logits[3 * i + 1], x2 = logits[3 * i + 2];
        const int tg = tgt[i];
        int pred = 0;
        float best = x0;
        if (x1 > best) { best = x1; pred = 1; }
        if (x2 > best) { best = x2; pred = 2; }
        const float e0 = __expf(x0 - best), e1 = __expf(x1 - best), e2 = __expf(x2 - best);
        const float lse = best + __logf(e0 + e1 + e2);
        const float xt = (tg == 0) ? x0 : ((tg == 1) ? x1 : x2);
        ce += (double)(lse - xt);
        float pv;
        if (tg == 0)      pv = (float)pred;
        else if (tg == 1) pv = (pred == 0) ? 5.0f : ((pred == 1) ? 0.0f : 1.0f);
        else              pv = (pred == 0) ? 20.0f : ((pred == 1) ? 10.0f : 0.0f);
        pen += (double)pv;
        cr += (tg == 2);
        mi += (tg == 2) && (pred != 2);
    }

    const float inv_b = 1.0f / (float)total;
    const float ce_loss = (float)(ce * (double)inv_b);
    const float safety  = (float)(pen * (double)inv_b);
    const float crit_pen = (cr > 0u) ? ((float)mi / (float)(cr > 0u ? cr : 1u) * 20.0f) : 0.0f;
    out[0] = ce_loss + 0.3f * safety + 0.5f * crit_pen;
}

extern "C" void kernel_launch(void* const* d_in, const int* in_sizes, int n_in,
                              void* d_out, int out_size, void* d_ws, size_t ws_size,
                              hipStream_t stream) {
    const float* logits = (const float*)d_in[0];
    const int*   tgt    = (const int*)d_in[1];
    const int B = in_sizes[1];           // number of samples (targets element count)

    double*       ws_d = (double*)d_ws;                  // [0]=ce_sum [1]=pen_sum
    unsigned int* ws_u = (unsigned int*)((char*)d_ws + 16); // [0]=crit [1]=miss

    hipMemsetAsync(d_ws, 0, 32, stream);

    const int nquads = B / 4;
    int blocks = (nquads + 255) / 256;
    if (blocks > 2048) blocks = 2048;
    if (blocks < 1) blocks = 1;

    loss_main_kernel<<<blocks, 256, 0, stream>>>(logits, tgt, nquads, ws_d, ws_u);
    loss_final_kernel<<<1, 1, 0, stream>>>(ws_d, ws_u, logits, tgt, nquads * 4, B,
                                           (float*)d_out);
}

// Round 2
// 23.026 us; speedup vs baseline: 4.9282x; 4.9282x over previous
//
#include <hip/hip_runtime.h>

// ClinicalSafetyLoss: fused CE + penalty-matrix + critical-miss reduction.
// R2: removed same-address global atomics (theory: 2048-contender device-scope
// atomic serialization tail caused ~90us idle). Per-block float4 partials in
// d_ws + single-block tree-reduce finalize. No atomics anywhere.

__device__ __forceinline__ float wave_reduce_f(float v) {
#pragma unroll
    for (int off = 32; off > 0; off >>= 1) v += __shfl_down(v, off, 64);
    return v;
}
__device__ __forceinline__ double wave_reduce_d(double v) {
#pragma unroll
    for (int off = 32; off > 0; off >>= 1) v += __shfl_down(v, off, 64);
    return v;
}

__global__ void __launch_bounds__(256) loss_main_kernel(
    const float* __restrict__ logits, const int* __restrict__ tgt,
    int nquads, float4* __restrict__ partials) {
    float ce = 0.0f, pen = 0.0f;
    int crit = 0, miss = 0;

    const float4* lv = reinterpret_cast<const float4*>(logits);
    const int4*   tv = reinterpret_cast<const int4*>(tgt);

    const int stride = gridDim.x * blockDim.x;
    for (int q = blockIdx.x * blockDim.x + threadIdx.x; q < nquads; q += stride) {
        // 4 samples = 12 floats = 3 x float4 (48B/thread, 16B-aligned), 1 x int4
        float4 a = lv[3 * q + 0];
        float4 b = lv[3 * q + 1];
        float4 c = lv[3 * q + 2];
        int4   t4 = tv[q];

        float x[12] = {a.x, a.y, a.z, a.w, b.x, b.y, b.z, b.w, c.x, c.y, c.z, c.w};
        int   t[4]  = {t4.x, t4.y, t4.z, t4.w};

#pragma unroll
        for (int s = 0; s < 4; ++s) {   // fully unrolled -> static indices (regs, no scratch)
            const float x0 = x[3 * s + 0], x1 = x[3 * s + 1], x2 = x[3 * s + 2];
            const int tg = t[s];

            // argmax, first-occurrence on ties (strict >) == jnp.argmax
            int pred = 0;
            float best = x0;
            if (x1 > best) { best = x1; pred = 1; }
            if (x2 > best) { best = x2; pred = 2; }

            // log-sum-exp (max-subtracted)
            const float e0 = __expf(x0 - best);
            const float e1 = __expf(x1 - best);
            const float e2 = __expf(x2 - best);
            const float lse = best + __logf(e0 + e1 + e2);
            const float xt = (tg == 0) ? x0 : ((tg == 1) ? x1 : x2);
            ce += (lse - xt);   // -logp[target]

            // PENALTY_MATRIX[tg][pred] via select chain (no memory, no scratch array)
            float pv;
            if (tg == 0)      pv = (float)pred;                                   // 0,1,2
            else if (tg == 1) pv = (pred == 0) ? 5.0f : ((pred == 1) ? 0.0f : 1.0f);
            else              pv = (pred == 0) ? 20.0f : ((pred == 1) ? 10.0f : 0.0f);
            pen += pv;

            const int is_crit = (tg == 2);
            crit += is_crit;
            miss += is_crit & (pred != 2);
        }
    }

    // wave -> block reduction, then ONE partial store per block (no atomics)
    ce = wave_reduce_f(ce);
    pen = wave_reduce_f(pen);
    float fcrit = wave_reduce_f((float)crit);   // exact: counts << 2^24
    float fmiss = wave_reduce_f((float)miss);

    __shared__ float4 s_part[4];
    const int lane = threadIdx.x & 63;
    const int wid  = threadIdx.x >> 6;
    if (lane == 0) s_part[wid] = make_float4(ce, pen, fcrit, fmiss);
    __syncthreads();
    if (threadIdx.x == 0) {
        float4 r = s_part[0];
#pragma unroll
        for (int i = 1; i < 4; ++i) {
            r.x += s_part[i].x; r.y += s_part[i].y;
            r.z += s_part[i].z; r.w += s_part[i].w;
        }
        partials[blockIdx.x] = r;
    }
}

__global__ void __launch_bounds__(256) loss_final_kernel(
    const float4* __restrict__ partials, int nblocks,
    const float* __restrict__ logits, const int* __restrict__ tgt,
    int start, int total, float* __restrict__ out) {
    double ce = 0.0, pen = 0.0, cr = 0.0, mi = 0.0;
    for (int i = threadIdx.x; i < nblocks; i += 256) {
        float4 p = partials[i];
        ce += (double)p.x; pen += (double)p.y;
        cr += (double)p.z; mi += (double)p.w;
    }
    ce = wave_reduce_d(ce); pen = wave_reduce_d(pen);
    cr = wave_reduce_d(cr); mi = wave_reduce_d(mi);

    __shared__ double sd[4][4];
    const int lane = threadIdx.x & 63;
    const int wid  = threadIdx.x >> 6;
    if (lane == 0) { sd[wid][0] = ce; sd[wid][1] = pen; sd[wid][2] = cr; sd[wid][3] = mi; }
    __syncthreads();
    if (threadIdx.x == 0) {
#pragma unroll
        for (int i = 1; i < 4; ++i) {
            sd[0][0] += sd[i][0]; sd[0][1] += sd[i][1];
            sd[0][2] += sd[i][2]; sd[0][3] += sd[i][3];
        }
        ce = sd[0][0]; pen = sd[0][1]; cr = sd[0][2]; mi = sd[0][3];

        // scalar tail (B % 4 != 0); B = 4194304 -> empty loop
        for (int i = start; i < total; ++i) {
            const float x0 = logits[3 * i + 0], x1 = logits[3 * i + 1], x2 = logits[3 * i + 2];
            const int tg = tgt[i];
            int pred = 0;
            float best = x0;
            if (x1 > best) { best = x1; pred = 1; }
            if (x2 > best) { best = x2; pred = 2; }
            const float e0 = __expf(x0 - best), e1 = __expf(x1 - best), e2 = __expf(x2 - best);
            const float lse = best + __logf(e0 + e1 + e2);
            const float xt = (tg == 0) ? x0 : ((tg == 1) ? x1 : x2);
            ce += (double)(lse - xt);
            float pv;
            if (tg == 0)      pv = (float)pred;
            else if (tg == 1) pv = (pred == 0) ? 5.0f : ((pred == 1) ? 0.0f : 1.0f);
            else              pv = (pred == 0) ? 20.0f : ((pred == 1) ? 10.0f : 0.0f);
            pen += (double)pv;
            cr += (double)(tg == 2);
            mi += (double)((tg == 2) && (pred != 2));
        }

        const double inv_b = 1.0 / (double)total;
        const double ce_loss = ce * inv_b;
        const double safety  = pen * inv_b;
        const double crit_pen = (cr > 0.0) ? (mi / cr * 20.0) : 0.0;
        out[0] = (float)(ce_loss + 0.3 * safety + 0.5 * crit_pen);
    }
}

extern "C" void kernel_launch(void* const* d_in, const int* in_sizes, int n_in,
                              void* d_out, int out_size, void* d_ws, size_t ws_size,
                              hipStream_t stream) {
    const float* logits = (const float*)d_in[0];
    const int*   tgt    = (const int*)d_in[1];
    const int B = in_sizes[1];           // number of samples (targets element count)

    float4* partials = (float4*)d_ws;

    const int nquads = B / 4;
    int blocks = (nquads + 255) / 256;   // 4096 at B=4.19M -> exactly 1 quad/thread
    const int maxp = (int)(ws_size / sizeof(float4));
    if (blocks > maxp) blocks = maxp;    // grid-stride loop covers the remainder
    if (blocks < 1) blocks = 1;

    loss_main_kernel<<<blocks, 256, 0, stream>>>(logits, tgt, nquads, partials);
    loss_final_kernel<<<1, 256, 0, stream>>>(partials, blocks, logits, tgt,
                                             nquads * 4, B, (float*)d_out);
}

// Round 3
// 21.115 us; speedup vs baseline: 5.3743x; 1.0905x over previous
//
#include <hip/hip_runtime.h>

// ClinicalSafetyLoss: fused CE + penalty-matrix + critical-miss reduction.
// R3: main grid = 2048 blocks (exactly 8/CU co-resident, 100% occupancy),
// 2 quads/thread grid-stride. Finalize reads 2048 L2-hot partials with full
// block parallelism. No atomics anywhere.

__device__ __forceinline__ float wave_reduce_f(float v) {
#pragma unroll
    for (int off = 32; off > 0; off >>= 1) v += __shfl_down(v, off, 64);
    return v;
}
__device__ __forceinline__ double wave_reduce_d(double v) {
#pragma unroll
    for (int off = 32; off > 0; off >>= 1) v += __shfl_down(v, off, 64);
    return v;
}

__device__ __forceinline__ void process_quad(const float4 a, const float4 b,
                                             const float4 c, const int4 t4,
                                             float& ce, float& pen,
                                             int& crit, int& miss) {
    const float x[12] = {a.x, a.y, a.z, a.w, b.x, b.y, b.z, b.w, c.x, c.y, c.z, c.w};
    const int   t[4]  = {t4.x, t4.y, t4.z, t4.w};
#pragma unroll
    for (int s = 0; s < 4; ++s) {   // fully unrolled -> static indices (regs, no scratch)
        const float x0 = x[3 * s + 0], x1 = x[3 * s + 1], x2 = x[3 * s + 2];
        const int tg = t[s];

        // argmax, first-occurrence on ties (strict >) == jnp.argmax
        int pred = 0;
        float best = x0;
        if (x1 > best) { best = x1; pred = 1; }
        if (x2 > best) { best = x2; pred = 2; }

        // log-sum-exp (max-subtracted)
        const float e0 = __expf(x0 - best);
        const float e1 = __expf(x1 - best);
        const float e2 = __expf(x2 - best);
        const float lse = best + __logf(e0 + e1 + e2);
        const float xt = (tg == 0) ? x0 : ((tg == 1) ? x1 : x2);
        ce += (lse - xt);   // -logp[target]

        // PENALTY_MATRIX[tg][pred] via select chain (no memory, no scratch array)
        float pv;
        if (tg == 0)      pv = (float)pred;                                    // 0,1,2
        else if (tg == 1) pv = (pred == 0) ? 5.0f : ((pred == 1) ? 0.0f : 1.0f);
        else              pv = (pred == 0) ? 20.0f : ((pred == 1) ? 10.0f : 0.0f);
        pen += pv;

        const int is_crit = (tg == 2);
        crit += is_crit;
        miss += is_crit & (pred != 2);
    }
}

__global__ void __launch_bounds__(256) loss_main_kernel(
    const float* __restrict__ logits, const int* __restrict__ tgt,
    int nquads, float4* __restrict__ partials) {
    float ce = 0.0f, pen = 0.0f;
    int crit = 0, miss = 0;

    const float4* lv = reinterpret_cast<const float4*>(logits);
    const int4*   tv = reinterpret_cast<const int4*>(tgt);

    const int stride = gridDim.x * blockDim.x;
    for (int q = blockIdx.x * blockDim.x + threadIdx.x; q < nquads; q += stride) {
        // 4 samples = 12 floats = 3 x float4 (48B/thread, 16B-aligned), 1 x int4
        const float4 a = lv[3 * q + 0];
        const float4 b = lv[3 * q + 1];
        const float4 c = lv[3 * q + 2];
        const int4   t4 = tv[q];
        process_quad(a, b, c, t4, ce, pen, crit, miss);
    }

    // wave -> block reduction, then ONE partial store per block (no atomics)
    ce = wave_reduce_f(ce);
    pen = wave_reduce_f(pen);
    float fcrit = wave_reduce_f((float)crit);   // exact: counts << 2^24
    float fmiss = wave_reduce_f((float)miss);

    __shared__ float4 s_part[4];
    const int lane = threadIdx.x & 63;
    const int wid  = threadIdx.x >> 6;
    if (lane == 0) s_part[wid] = make_float4(ce, pen, fcrit, fmiss);
    __syncthreads();
    if (threadIdx.x == 0) {
        float4 r = s_part[0];
#pragma unroll
        for (int i = 1; i < 4; ++i) {
            r.x += s_part[i].x; r.y += s_part[i].y;
            r.z += s_part[i].z; r.w += s_part[i].w;
        }
        partials[blockIdx.x] = r;
    }
}

__global__ void __launch_bounds__(256) loss_final_kernel(
    const float4* __restrict__ partials, int nblocks,
    const float* __restrict__ logits, const int* __restrict__ tgt,
    int start, int total, float* __restrict__ out) {
    double ce = 0.0, pen = 0.0, cr = 0.0, mi = 0.0;
    for (int i = threadIdx.x; i < nblocks; i += 256) {   // 8 L2-hot f4 loads/thread, full ILP
        const float4 p = partials[i];
        ce += (double)p.x; pen += (double)p.y;
        cr += (double)p.z; mi += (double)p.w;
    }
    ce = wave_reduce_d(ce); pen = wave_reduce_d(pen);
    cr = wave_reduce_d(cr); mi = wave_reduce_d(mi);

    __shared__ double sd[4][4];
    const int lane = threadIdx.x & 63;
    const int wid  = threadIdx.x >> 6;
    if (lane == 0) { sd[wid][0] = ce; sd[wid][1] = pen; sd[wid][2] = cr; sd[wid][3] = mi; }
    __syncthreads();
    if (threadIdx.x == 0) {
#pragma unroll
        for (int i = 1; i < 4; ++i) {
            sd[0][0] += sd[i][0]; sd[0][1] += sd[i][1];
            sd[0][2] += sd[i][2]; sd[0][3] += sd[i][3];
        }
        ce = sd[0][0]; pen = sd[0][1]; cr = sd[0][2]; mi = sd[0][3];

        // scalar tail (B % 4 != 0); B = 4194304 -> empty loop
        for (int i = start; i < total; ++i) {
            const float x0 = logits[3 * i + 0], x1 = logits[3 * i + 1], x2 = logits[3 * i + 2];
            const int tg = tgt[i];
            int pred = 0;
            float best = x0;
            if (x1 > best) { best = x1; pred = 1; }
            if (x2 > best) { best = x2; pred = 2; }
            const float e0 = __expf(x0 - best), e1 = __expf(x1 - best), e2 = __expf(x2 - best);
            const float lse = best + __logf(e0 + e1 + e2);
            const float xt = (tg == 0) ? x0 : ((tg == 1) ? x1 : x2);
            ce += (double)(lse - xt);
            float pv;
            if (tg == 0)      pv = (float)pred;
            else if (tg == 1) pv = (pred == 0) ? 5.0f : ((pred == 1) ? 0.0f : 1.0f);
            else              pv = (pred == 0) ? 20.0f : ((pred == 1) ? 10.0f : 0.0f);
            pen += (double)pv;
            cr += (double)(tg == 2);
            mi += (double)((tg == 2) && (pred != 2));
        }

        const double inv_b = 1.0 / (double)total;
        const double ce_loss = ce * inv_b;
        const double safety  = pen * inv_b;
        const double crit_pen = (cr > 0.0) ? (mi / cr * 20.0) : 0.0;
        out[0] = (float)(ce_loss + 0.3 * safety + 0.5 * crit_pen);
    }
}

extern "C" void kernel_launch(void* const* d_in, const int* in_sizes, int n_in,
                              void* d_out, int out_size, void* d_ws, size_t ws_size,
                              hipStream_t stream) {
    const float* logits = (const float*)d_in[0];
    const int*   tgt    = (const int*)d_in[1];
    const int B = in_sizes[1];           // number of samples (targets element count)

    float4* partials = (float4*)d_ws;

    const int nquads = B / 4;
    // 2048 blocks x 256 thr = 8 blocks/CU on 256 CUs -> exactly 32 waves/CU
    // co-resident from t=0; 2 quads/thread via grid-stride at B=4.19M.
    int blocks = 2048;
    const int needed = (nquads + 255) / 256;
    if (blocks > needed) blocks = needed;
    const int maxp = (int)(ws_size / sizeof(float4));
    if (blocks > maxp) blocks = maxp;
    if (blocks < 1) blocks = 1;

    loss_main_kernel<<<blocks, 256, 0, stream>>>(logits, tgt, nquads, partials);
    loss_final_kernel<<<1, 256, 0, stream>>>(partials, blocks, logits, tgt,
                                             nquads * 4, B, (float*)d_out);
}

// Round 4
// 20.946 us; speedup vs baseline: 5.4177x; 1.0081x over previous
//
#include <hip/hip_runtime.h>

// ClinicalSafetyLoss: fused CE + penalty-matrix + critical-miss reduction.
// R4: coalesced logit loads via LDS staging. Each block-iter stages 768
// consecutive float4 (3 coalesced wave loads) into 12KB LDS with XOR granule
// swizzle p(g)=g^((g>>3)&7) so the per-thread 3xds_read_b128 (granules
// 3t,3t+1,3t+2) is bank-conflict-free. Targets load direct (int4/lane is
// already coalesced). No atomics anywhere.

__device__ __forceinline__ float wave_reduce_f(float v) {
#pragma unroll
    for (int off = 32; off > 0; off >>= 1) v += __shfl_down(v, off, 64);
    return v;
}
__device__ __forceinline__ double wave_reduce_d(double v) {
#pragma unroll
    for (int off = 32; off > 0; off >>= 1) v += __shfl_down(v, off, 64);
    return v;
}

__device__ __forceinline__ void process_quad(const float4 a, const float4 b,
                                             const float4 c, const int4 t4,
                                             float& ce, float& pen,
                                             int& crit, int& miss) {
    const float x[12] = {a.x, a.y, a.z, a.w, b.x, b.y, b.z, b.w, c.x, c.y, c.z, c.w};
    const int   t[4]  = {t4.x, t4.y, t4.z, t4.w};
#pragma unroll
    for (int s = 0; s < 4; ++s) {   // fully unrolled -> static indices (regs, no scratch)
        const float x0 = x[3 * s + 0], x1 = x[3 * s + 1], x2 = x[3 * s + 2];
        const int tg = t[s];

        // argmax, first-occurrence on ties (strict >) == jnp.argmax
        int pred = 0;
        float best = x0;
        if (x1 > best) { best = x1; pred = 1; }
        if (x2 > best) { best = x2; pred = 2; }

        // log-sum-exp (max-subtracted)
        const float e0 = __expf(x0 - best);
        const float e1 = __expf(x1 - best);
        const float e2 = __expf(x2 - best);
        const float lse = best + __logf(e0 + e1 + e2);
        const float xt = (tg == 0) ? x0 : ((tg == 1) ? x1 : x2);
        ce += (lse - xt);   // -logp[target]

        // PENALTY_MATRIX[tg][pred] via select chain (no memory, no scratch array)
        float pv;
        if (tg == 0)      pv = (float)pred;                                    // 0,1,2
        else if (tg == 1) pv = (pred == 0) ? 5.0f : ((pred == 1) ? 0.0f : 1.0f);
        else              pv = (pred == 0) ? 20.0f : ((pred == 1) ? 10.0f : 0.0f);
        pen += pv;

        const int is_crit = (tg == 2);
        crit += is_crit;
        miss += is_crit & (pred != 2);
    }
}

__device__ __forceinline__ int swz(int g) { return g ^ ((g >> 3) & 7); }

__global__ void __launch_bounds__(256) loss_main_kernel(
    const float* __restrict__ logits, const int* __restrict__ tgt,
    int nchunks, float4* __restrict__ partials) {
    float ce = 0.0f, pen = 0.0f;
    int crit = 0, miss = 0;

    const float4* lv = reinterpret_cast<const float4*>(logits);
    const int4*   tv = reinterpret_cast<const int4*>(tgt);

    // chunk = 1024 samples = 768 float4 logits (12KB) + 256 int4 targets
    __shared__ float4 s_f4[768];

    for (int chunk = blockIdx.x; chunk < nchunks; chunk += gridDim.x) {
        const float4* src = lv + (size_t)chunk * 768;
        // 3 fully-coalesced wave loads -> swizzled LDS store
#pragma unroll
        for (int s = 0; s < 3; ++s) {
            const int g = threadIdx.x + 256 * s;
            s_f4[swz(g)] = src[g];
        }
        const int4 t4 = tv[(size_t)chunk * 256 + threadIdx.x];
        __syncthreads();

        const int g0 = 3 * threadIdx.x;
        const float4 a = s_f4[swz(g0 + 0)];
        const float4 b = s_f4[swz(g0 + 1)];
        const float4 c = s_f4[swz(g0 + 2)];
        process_quad(a, b, c, t4, ce, pen, crit, miss);
        __syncthreads();   // protect LDS before next iteration's writes
    }

    // wave -> block reduction, then ONE partial store per block (no atomics)
    ce = wave_reduce_f(ce);
    pen = wave_reduce_f(pen);
    float fcrit = wave_reduce_f((float)crit);   // exact: counts << 2^24
    float fmiss = wave_reduce_f((float)miss);

    __shared__ float4 s_part[4];
    const int lane = threadIdx.x & 63;
    const int wid  = threadIdx.x >> 6;
    if (lane == 0) s_part[wid] = make_float4(ce, pen, fcrit, fmiss);
    __syncthreads();
    if (threadIdx.x == 0) {
        float4 r = s_part[0];
#pragma unroll
        for (int i = 1; i < 4; ++i) {
            r.x += s_part[i].x; r.y += s_part[i].y;
            r.z += s_part[i].z; r.w += s_part[i].w;
        }
        partials[blockIdx.x] = r;
    }
}

__global__ void __launch_bounds__(256) loss_final_kernel(
    const float4* __restrict__ partials, int nblocks,
    const float* __restrict__ logits, const int* __restrict__ tgt,
    int start, int total, float* __restrict__ out) {
    double ce = 0.0, pen = 0.0, cr = 0.0, mi = 0.0;
    for (int i = threadIdx.x; i < nblocks; i += 256) {   // L2-hot f4 loads, full ILP
        const float4 p = partials[i];
        ce += (double)p.x; pen += (double)p.y;
        cr += (double)p.z; mi += (double)p.w;
    }
    ce = wave_reduce_d(ce); pen = wave_reduce_d(pen);
    cr = wave_reduce_d(cr); mi = wave_reduce_d(mi);

    __shared__ double sd[4][4];
    const int lane = threadIdx.x & 63;
    const int wid  = threadIdx.x >> 6;
    if (lane == 0) { sd[wid][0] = ce; sd[wid][1] = pen; sd[wid][2] = cr; sd[wid][3] = mi; }
    __syncthreads();
    if (threadIdx.x == 0) {
#pragma unroll
        for (int i = 1; i < 4; ++i) {
            sd[0][0] += sd[i][0]; sd[0][1] += sd[i][1];
            sd[0][2] += sd[i][2]; sd[0][3] += sd[i][3];
        }
        ce = sd[0][0]; pen = sd[0][1]; cr = sd[0][2]; mi = sd[0][3];

        // scalar tail (B % 1024 != 0); B = 4194304 -> empty loop
        for (int i = start; i < total; ++i) {
            const float x0 = logits[3 * i + 0], x1 = logits[3 * i + 1], x2 = logits[3 * i + 2];
            const int tg = tgt[i];
            int pred = 0;
            float best = x0;
            if (x1 > best) { best = x1; pred = 1; }
            if (x2 > best) { best = x2; pred = 2; }
            const float e0 = __expf(x0 - best), e1 = __expf(x1 - best), e2 = __expf(x2 - best);
            const float lse = best + __logf(e0 + e1 + e2);
            const float xt = (tg == 0) ? x0 : ((tg == 1) ? x1 : x2);
            ce += (double)(lse - xt);
            float pv;
            if (tg == 0)      pv = (float)pred;
            else if (tg == 1) pv = (pred == 0) ? 5.0f : ((pred == 1) ? 0.0f : 1.0f);
            else              pv = (pred == 0) ? 20.0f : ((pred == 1) ? 10.0f : 0.0f);
            pen += (double)pv;
            cr += (double)(tg == 2);
            mi += (double)((tg == 2) && (pred != 2));
        }

        const double inv_b = 1.0 / (double)total;
        const double ce_loss = ce * inv_b;
        const double safety  = pen * inv_b;
        const double crit_pen = (cr > 0.0) ? (mi / cr * 20.0) : 0.0;
        out[0] = (float)(ce_loss + 0.3 * safety + 0.5 * crit_pen);
    }
}

extern "C" void kernel_launch(void* const* d_in, const int* in_sizes, int n_in,
                              void* d_out, int out_size, void* d_ws, size_t ws_size,
                              hipStream_t stream) {
    const float* logits = (const float*)d_in[0];
    const int*   tgt    = (const int*)d_in[1];
    const int B = in_sizes[1];           // number of samples (targets element count)

    float4* partials = (float4*)d_ws;

    const int nchunks = B / 1024;        // 1024 samples per block-iteration
    // 2048 blocks x 256 thr = 8 blocks/CU on 256 CUs = 32 waves/CU co-resident;
    // 2 chunks/block at B=4.19M.
    int blocks = 2048;
    if (blocks > nchunks) blocks = nchunks;
    const int maxp = (int)(ws_size / sizeof(float4));
    if (blocks > maxp) blocks = maxp;
    if (blocks < 1) blocks = 1;

    loss_main_kernel<<<blocks, 256, 0, stream>>>(logits, tgt, nchunks, partials);
    loss_final_kernel<<<1, 256, 0, stream>>>(partials, blocks, logits, tgt,
                                             nchunks * 1024, B, (float*)d_out);
}